// Round 1
// baseline (1570.865 us; speedup 1.0000x reference)
//
#include <hip/hip_runtime.h>
#include <hip/hip_bf16.h>

typedef __hip_bfloat16 bf16;

#define NB   2
#define NG   192
#define DD   256
#define NN2  (NG*NG)          // 36864
#define MT   (NB*NN2)         // 73728

static __device__ __forceinline__ float bfu2f(unsigned short u){
    return __uint_as_float(((unsigned)u) << 16);
}

// ------------------------------------------------------------------
// Projections: out = act(E @ W^T + b), stored bf16.  p: 0=q 1=k 2=v 3=g(sigmoid)
// ------------------------------------------------------------------
__global__ __launch_bounds__(256) void k_proj(
    const float* __restrict__ E,
    const float* __restrict__ Wq, const float* __restrict__ bq,
    const float* __restrict__ Wk, const float* __restrict__ bk,
    const float* __restrict__ Wv, const float* __restrict__ bv,
    const float* __restrict__ Wg, const float* __restrict__ bg,
    bf16* __restrict__ qb, bf16* __restrict__ kb,
    bf16* __restrict__ vb, bf16* __restrict__ gb)
{
    const int p = blockIdx.z;
    const float* W; const float* bias; bf16* out;
    switch (p){
      case 0:  W=Wq; bias=bq; out=qb; break;
      case 1:  W=Wk; bias=bk; out=kb; break;
      case 2:  W=Wv; bias=bv; out=vb; break;
      default: W=Wg; bias=bg; out=gb; break;
    }
    __shared__ float Es[64][17];
    __shared__ float Ws[64][17];
    const int row0 = blockIdx.x*64;
    const int col0 = blockIdx.y*64;
    const int tid  = threadIdx.x;
    const int tx = tid & 15, ty = tid >> 4;
    const int lr = tid >> 2, lq = tid & 3;

    float acc[4][4] = {};

    for (int k0 = 0; k0 < DD; k0 += 16){
        float4 ev = *((const float4*)(E + (size_t)(row0+lr)*DD + k0) + lq);
        float4 wv = *((const float4*)(W + (size_t)(col0+lr)*DD + k0) + lq);
        Es[lr][lq*4+0]=ev.x; Es[lr][lq*4+1]=ev.y; Es[lr][lq*4+2]=ev.z; Es[lr][lq*4+3]=ev.w;
        Ws[lr][lq*4+0]=wv.x; Ws[lr][lq*4+1]=wv.y; Ws[lr][lq*4+2]=wv.z; Ws[lr][lq*4+3]=wv.w;
        __syncthreads();
        #pragma unroll
        for (int kk=0;kk<16;kk++){
            float a[4], b[4];
            #pragma unroll
            for (int r=0;r<4;r++) a[r]=Es[ty*4+r][kk];
            #pragma unroll
            for (int c=0;c<4;c++) b[c]=Ws[tx*4+c][kk];
            #pragma unroll
            for (int r=0;r<4;r++)
                #pragma unroll
                for (int c=0;c<4;c++) acc[r][c] += a[r]*b[c];
        }
        __syncthreads();
    }
    #pragma unroll
    for (int r=0;r<4;r++){
        int m = row0 + ty*4 + r;
        #pragma unroll
        for (int c=0;c<4;c++){
            int o = col0 + tx*4 + c;
            float v = acc[r][c] + bias[o];
            if (p==3) v = 1.0f/(1.0f+__expf(-v));
            out[(size_t)m*DD + o] = __float2bfloat16(v);
        }
    }
}

// ------------------------------------------------------------------
// bmat GEMV: bm[m] = E[m,:] . Wb + bb     (one wave per row)
// ------------------------------------------------------------------
__global__ __launch_bounds__(256) void k_bmat(
    const float* __restrict__ E, const float* __restrict__ Wb,
    const float* __restrict__ bb, float* __restrict__ bm)
{
    int row  = blockIdx.x*4 + (threadIdx.x >> 6);
    int lane = threadIdx.x & 63;
    float4 e = ((const float4*)(E + (size_t)row*DD))[lane];
    float4 w = ((const float4*)Wb)[lane];
    float s = e.x*w.x + e.y*w.y + e.z*w.z + e.w*w.w;
    #pragma unroll
    for (int off=32; off; off>>=1) s += __shfl_down(s, off);
    if (lane==0) bm[row] = s + bb[0];
}

// ------------------------------------------------------------------
// Generic 64x64 NT tile: C = A(64xK) . B(64xK)^T ; A,B bf16 K-contiguous
// ------------------------------------------------------------------
static __device__ __forceinline__ void gemm_nt_tile(
    const bf16* __restrict__ A, size_t Ast,
    const bf16* __restrict__ B, size_t Bst,
    float* __restrict__ C, size_t Cst, bool accum)
{
    __shared__ float As[64][17];
    __shared__ float Bs[64][17];
    const int tid = threadIdx.x;
    const int tx = tid & 15, ty = tid >> 4;
    const int lr = tid >> 2, lq = tid & 3;
    float acc[4][4] = {};
    for (int k0=0;k0<DD;k0+=16){
        ushort4 av = *((const ushort4*)(A + lr*Ast + k0) + lq);
        ushort4 bv = *((const ushort4*)(B + lr*Bst + k0) + lq);
        As[lr][lq*4+0]=bfu2f(av.x); As[lr][lq*4+1]=bfu2f(av.y);
        As[lr][lq*4+2]=bfu2f(av.z); As[lr][lq*4+3]=bfu2f(av.w);
        Bs[lr][lq*4+0]=bfu2f(bv.x); Bs[lr][lq*4+1]=bfu2f(bv.y);
        Bs[lr][lq*4+2]=bfu2f(bv.z); Bs[lr][lq*4+3]=bfu2f(bv.w);
        __syncthreads();
        #pragma unroll
        for (int kk=0;kk<16;kk++){
            float a[4], b[4];
            #pragma unroll
            for (int r=0;r<4;r++) a[r]=As[ty*4+r][kk];
            #pragma unroll
            for (int c=0;c<4;c++) b[c]=Bs[tx*4+c][kk];
            #pragma unroll
            for (int r=0;r<4;r++)
                #pragma unroll
                for (int c=0;c<4;c++) acc[r][c] += a[r]*b[c];
        }
        __syncthreads();
    }
    #pragma unroll
    for (int r=0;r<4;r++){
        float* cp = C + (size_t)(ty*4+r)*Cst + tx*4;
        #pragma unroll
        for (int c=0;c<4;c++){
            if (accum) cp[c] += acc[r][c];
            else       cp[c]  = acc[r][c];
        }
    }
}

// term1[b,i,j,l] = q[b,i,j,:] . k[b,i,l,:]
__global__ __launch_bounds__(256) void k_term1(
    const bf16* __restrict__ qb, const bf16* __restrict__ kb, float* __restrict__ alpha)
{
    int bi = blockIdx.z;                    // b*NG + i
    int j0 = blockIdx.x*64, l0 = blockIdx.y*64;
    const bf16* A = qb + ((size_t)bi*NG + j0)*DD;
    const bf16* B = kb + ((size_t)bi*NG + l0)*DD;
    float* C = alpha + ((size_t)bi*NG + j0)*NG + l0;
    gemm_nt_tile(A, DD, B, DD, C, NG, false);
}

// term2[b,i,j,l] += q[b,i,j,:] . k[b,l,j,:]   (batched over (b,j))
__global__ __launch_bounds__(256) void k_term2(
    const bf16* __restrict__ qb, const bf16* __restrict__ kb, float* __restrict__ alpha)
{
    int bj = blockIdx.z; int b = bj/NG, j = bj%NG;
    int i0 = blockIdx.x*64, l0 = blockIdx.y*64;
    const bf16* A = qb + (((size_t)b*NG + i0)*NG + j)*DD;
    const bf16* B = kb + (((size_t)b*NG + l0)*NG + j)*DD;
    float* C = alpha + (((size_t)b*NG + i0)*NG + j)*NG + l0;
    gemm_nt_tile(A, (size_t)NG*DD, B, (size_t)NG*DD, C, (size_t)NN2, true);
}

// ------------------------------------------------------------------
// softmax over l with bias bm[b,i,l]+bm[b,l,i]; scale 1/16 on scores
// one wave per (b,i,j) row
// ------------------------------------------------------------------
__global__ __launch_bounds__(256) void k_softmax(
    float* __restrict__ alpha, const float* __restrict__ bm)
{
    int row  = blockIdx.x*4 + (threadIdx.x >> 6);   // (b*NG + i)*NG + j
    int lane = threadIdx.x & 63;
    int b = row / NN2;
    int i = (row / NG) % NG;
    float* arow = alpha + (size_t)row*NG;
    const float* bmb = bm + (size_t)b*NN2;
    float vals[3];
    float mx = -1e30f;
    #pragma unroll
    for (int t=0;t<3;t++){
        int l = lane + t*64;
        float s = arow[l]*0.0625f + bmb[(size_t)i*NG + l] + bmb[(size_t)l*NG + i];
        vals[t] = s;
        mx = fmaxf(mx, s);
    }
    #pragma unroll
    for (int off=32; off; off>>=1) mx = fmaxf(mx, __shfl_xor(mx, off));
    float sum = 0.f;
    #pragma unroll
    for (int t=0;t<3;t++){ vals[t] = __expf(vals[t]-mx); sum += vals[t]; }
    #pragma unroll
    for (int off=32; off; off>>=1) sum += __shfl_xor(sum, off);
    float inv = 1.0f/sum;
    #pragma unroll
    for (int t=0;t<3;t++) arow[lane + t*64] = vals[t]*inv;
}

// ------------------------------------------------------------------
// h[b,i,j,d] = g * (A_i @ V_i + A'_i @ V'_i)   per (b,i); stored bf16
// ------------------------------------------------------------------
__global__ __launch_bounds__(256) void k_attnout(
    const float* __restrict__ alpha, const bf16* __restrict__ vb,
    const bf16* __restrict__ gb, bf16* __restrict__ hb)
{
    int bi = blockIdx.z; int b = bi/NG, i = bi%NG;
    int j0 = blockIdx.x*64, d0 = blockIdx.y*64;
    __shared__ float As[64][17];
    __shared__ float Vs[16][65];
    const int tid = threadIdx.x;
    const int tx = tid & 15, ty = tid >> 4;
    const int alr = tid >> 2,  alq = tid & 3;
    const int vlr = tid >> 4,  vlq = tid & 15;
    float acc[4][4] = {};

    const float* A1 = alpha + ((size_t)bi*NG + j0)*NG;                    // row j: +NG
    const bf16*  V1 = vb + ((size_t)bi*NG)*DD + d0;                       // row l: +DD
    const float* A2 = alpha + ((size_t)b*NG + j0)*NN2 + (size_t)i*NG;     // row j: +NN2
    const bf16*  V2 = vb + ((size_t)b*NG)*NG*DD + (size_t)i*DD + d0;      // row l: +NG*DD

    #pragma unroll
    for (int pass=0; pass<2; pass++){
        const float* A = pass ? A2 : A1; size_t Ast = pass ? (size_t)NN2 : (size_t)NG;
        const bf16*  V = pass ? V2 : V1; size_t Vst = pass ? (size_t)NG*DD : (size_t)DD;
        for (int l0=0; l0<NG; l0+=16){
            float4 av = *((const float4*)(A + (size_t)alr*Ast + l0) + alq);
            As[alr][alq*4+0]=av.x; As[alr][alq*4+1]=av.y;
            As[alr][alq*4+2]=av.z; As[alr][alq*4+3]=av.w;
            ushort4 vv = *((const ushort4*)(V + (size_t)(l0+vlr)*Vst) + vlq);
            Vs[vlr][vlq*4+0]=bfu2f(vv.x); Vs[vlr][vlq*4+1]=bfu2f(vv.y);
            Vs[vlr][vlq*4+2]=bfu2f(vv.z); Vs[vlr][vlq*4+3]=bfu2f(vv.w);
            __syncthreads();
            #pragma unroll
            for (int kk=0;kk<16;kk++){
                float a[4], v4[4];
                #pragma unroll
                for (int r=0;r<4;r++) a[r]=As[ty*4+r][kk];
                #pragma unroll
                for (int c=0;c<4;c++) v4[c]=Vs[kk][tx*4+c];
                #pragma unroll
                for (int r=0;r<4;r++)
                    #pragma unroll
                    for (int c=0;c<4;c++) acc[r][c] += a[r]*v4[c];
            }
            __syncthreads();
        }
    }
    #pragma unroll
    for (int r=0;r<4;r++){
        #pragma unroll
        for (int c=0;c<4;c++){
            size_t idx = ((size_t)bi*NG + j0+ty*4+r)*DD + d0+tx*4+c;
            hb[idx] = __float2bfloat16(bfu2f(*(const unsigned short*)&gb[idx]) * acc[r][c]);
        }
    }
}

// ------------------------------------------------------------------
// final: out = relu(h @ Wo^T + bo), f32 out
// ------------------------------------------------------------------
__global__ __launch_bounds__(256) void k_final(
    const bf16* __restrict__ hb, const float* __restrict__ Wo,
    const float* __restrict__ bo, float* __restrict__ out)
{
    __shared__ float Hs[64][17];
    __shared__ float Ws[64][17];
    const int row0 = blockIdx.x*64;
    const int col0 = blockIdx.y*64;
    const int tid  = threadIdx.x;
    const int tx = tid & 15, ty = tid >> 4;
    const int lr = tid >> 2, lq = tid & 3;
    float acc[4][4] = {};
    for (int k0=0;k0<DD;k0+=16){
        ushort4 hv = *((const ushort4*)(hb + (size_t)(row0+lr)*DD + k0) + lq);
        float4  wv = *((const float4*)(Wo + (size_t)(col0+lr)*DD + k0) + lq);
        Hs[lr][lq*4+0]=bfu2f(hv.x); Hs[lr][lq*4+1]=bfu2f(hv.y);
        Hs[lr][lq*4+2]=bfu2f(hv.z); Hs[lr][lq*4+3]=bfu2f(hv.w);
        Ws[lr][lq*4+0]=wv.x; Ws[lr][lq*4+1]=wv.y; Ws[lr][lq*4+2]=wv.z; Ws[lr][lq*4+3]=wv.w;
        __syncthreads();
        #pragma unroll
        for (int kk=0;kk<16;kk++){
            float a[4], b[4];
            #pragma unroll
            for (int r=0;r<4;r++) a[r]=Hs[ty*4+r][kk];
            #pragma unroll
            for (int c=0;c<4;c++) b[c]=Ws[tx*4+c][kk];
            #pragma unroll
            for (int r=0;r<4;r++)
                #pragma unroll
                for (int c=0;c<4;c++) acc[r][c] += a[r]*b[c];
        }
        __syncthreads();
    }
    #pragma unroll
    for (int r=0;r<4;r++){
        int m = row0 + ty*4 + r;
        #pragma unroll
        for (int c=0;c<4;c++){
            int o = col0 + tx*4 + c;
            float v = acc[r][c] + bo[o];
            out[(size_t)m*DD + o] = fmaxf(v, 0.0f);
        }
    }
}

// ------------------------------------------------------------------
extern "C" void kernel_launch(void* const* d_in, const int* in_sizes, int n_in,
                              void* d_out, int out_size, void* d_ws, size_t ws_size,
                              hipStream_t stream)
{
    const float* E  = (const float*)d_in[0];
    const float* Wq = (const float*)d_in[1];  const float* bq = (const float*)d_in[2];
    const float* Wk = (const float*)d_in[3];  const float* bk = (const float*)d_in[4];
    const float* Wv = (const float*)d_in[5];  const float* bv = (const float*)d_in[6];
    const float* Wb = (const float*)d_in[7];  const float* bb = (const float*)d_in[8];
    const float* Wg = (const float*)d_in[9];  const float* bg = (const float*)d_in[10];
    const float* Wo = (const float*)d_in[11]; const float* bo = (const float*)d_in[12];
    float* out = (float*)d_out;

    char* ws = (char*)d_ws;
    size_t off = 0;
    bf16* qb = (bf16*)(ws+off); off += (size_t)MT*DD*sizeof(bf16);
    bf16* kb = (bf16*)(ws+off); off += (size_t)MT*DD*sizeof(bf16);
    bf16* vb = (bf16*)(ws+off); off += (size_t)MT*DD*sizeof(bf16);
    bf16* gb = (bf16*)(ws+off); off += (size_t)MT*DD*sizeof(bf16);
    float* bm    = (float*)(ws+off); off += (size_t)MT*sizeof(float);
    float* alpha = (float*)(ws+off); off += (size_t)NB*NG*NG*NG*sizeof(float);
    bf16* hb = qb;   // q dead after term2 — reuse for gated output

    k_proj   <<<dim3(MT/64, DD/64, 4), 256, 0, stream>>>(E, Wq,bq, Wk,bk, Wv,bv, Wg,bg, qb,kb,vb,gb);
    k_bmat   <<<dim3(MT/4), 256, 0, stream>>>(E, Wb, bb, bm);
    k_term1  <<<dim3(NG/64, NG/64, NB*NG), 256, 0, stream>>>(qb, kb, alpha);
    k_term2  <<<dim3(NG/64, NG/64, NB*NG), 256, 0, stream>>>(qb, kb, alpha);
    k_softmax<<<dim3(MT/4), 256, 0, stream>>>(alpha, bm);
    k_attnout<<<dim3(NG/64, DD/64, NB*NG), 256, 0, stream>>>(alpha, vb, gb, hb);
    k_final  <<<dim3(MT/64, DD/64), 256, 0, stream>>>(hb, Wo, bo, out);
}

// Round 3
// 420.537 us; speedup vs baseline: 3.7354x; 3.7354x over previous
//
#include <hip/hip_runtime.h>
#include <hip/hip_bf16.h>

typedef __hip_bfloat16 bf16;
typedef unsigned short u16;
typedef __attribute__((ext_vector_type(8))) short bf16x8;
typedef __attribute__((ext_vector_type(4))) float f32x4;

#define NB   2
#define NG   192
#define DD   256
#define NN2  (NG*NG)          // 36864
#define MT   (NB*NN2)         // 73728

static __device__ __forceinline__ float bfu2f(u16 u){
    return __uint_as_float(((unsigned)u) << 16);
}
static __device__ __forceinline__ u16 f2bfu(float f){
    bf16 h = __float2bfloat16(f);
    return *(u16*)&h;
}

// async global->LDS, 16B per lane. LDS dest: wave-uniform base + lane*16.
static __device__ __forceinline__ void gl_lds16(const void* g, void* l){
    __builtin_amdgcn_global_load_lds(
        (const __attribute__((address_space(1))) unsigned int*)g,
        (__attribute__((address_space(3))) unsigned int*)l, 16, 0, 0);
}

// ------------------------------------------------------------------
// casts
// ------------------------------------------------------------------
__global__ __launch_bounds__(256) void k_cast_e(const float* __restrict__ E, u16* __restrict__ Eb){
    size_t i = ((size_t)blockIdx.x*256 + threadIdx.x)*8;
    float4 x = *(const float4*)(E+i);
    float4 y = *(const float4*)(E+i+4);
    ushort4 a; a.x=f2bfu(x.x); a.y=f2bfu(x.y); a.z=f2bfu(x.z); a.w=f2bfu(x.w);
    ushort4 b; b.x=f2bfu(y.x); b.y=f2bfu(y.y); b.z=f2bfu(y.z); b.w=f2bfu(y.w);
    *(ushort4*)(Eb+i)   = a;
    *(ushort4*)(Eb+i+4) = b;
}

__global__ __launch_bounds__(256) void k_cast_w(
    const float* __restrict__ Wq, const float* __restrict__ Wk,
    const float* __restrict__ Wv, const float* __restrict__ Wg,
    const float* __restrict__ Wo,
    const float* __restrict__ bq, const float* __restrict__ bk,
    const float* __restrict__ bv, const float* __restrict__ bg,
    u16* __restrict__ Wcat, u16* __restrict__ Wob, float* __restrict__ biascat)
{
    int e = blockIdx.x*256 + threadIdx.x;      // 65536 total
    Wcat[e]          = f2bfu(Wq[e]);
    Wcat[65536 + e]  = f2bfu(Wk[e]);
    Wcat[131072 + e] = f2bfu(Wv[e]);
    Wcat[196608 + e] = f2bfu(Wg[e]);
    Wob[e]           = f2bfu(Wo[e]);
    if (e < 1024){
        int p = e>>8, r = e&255;
        const float* bp = p==0?bq : p==1?bk : p==2?bv : bg;
        biascat[e] = bp[r];
    }
}

// ------------------------------------------------------------------
// 128x128 MFMA tile core (K=256): C = A(128xK) . B(128xK)^T
// 4 waves, each 64x64 = 4x4 frags of 16x16x32. LDS XOR-swizzled (rule #21:
// pre-swizzled global source + swizzled ds_read, linear gload_lds dest).
// ------------------------------------------------------------------
static __device__ __forceinline__ void gemm128_acc(
    const u16* __restrict__ A, size_t Ast,
    const u16* __restrict__ B, size_t Bst,
    u16* As, u16* Bs, f32x4 acc[4][4], int t)
{
    const int lane = t & 63, w = t >> 6;
    const int wm = (w>>1)*64, wn = (w&1)*64;
    int offA[4], offB[4];
    #pragma unroll
    for (int f=0; f<4; f++){
        int ra = wm + f*16 + (lane&15);
        offA[f] = ra*32 + (((lane>>4) ^ ((ra>>1)&3)) << 3);
        int rb = wn + f*16 + (lane&15);
        offB[f] = rb*32 + (((lane>>4) ^ ((rb>>1)&3)) << 3);
    }
    for (int k0=0; k0<DD; k0+=32){
        #pragma unroll
        for (int it=0; it<2; it++){
            int c = it*256 + t;
            int row = c >> 2;
            int ks  = (c&3) ^ ((row>>1)&3);
            gl_lds16(A + (size_t)row*Ast + k0 + ks*8, As + c*8);
            gl_lds16(B + (size_t)row*Bst + k0 + ks*8, Bs + c*8);
        }
        __syncthreads();
        bf16x8 a[4], b[4];
        #pragma unroll
        for (int f=0; f<4; f++) a[f] = *(const bf16x8*)(As + offA[f]);
        #pragma unroll
        for (int f=0; f<4; f++) b[f] = *(const bf16x8*)(Bs + offB[f]);
        #pragma unroll
        for (int mf=0; mf<4; mf++)
            #pragma unroll
            for (int nf=0; nf<4; nf++)
                acc[mf][nf] = __builtin_amdgcn_mfma_f32_16x16x32_bf16(a[mf], b[nf], acc[mf][nf], 0, 0, 0);
        __syncthreads();
    }
}

// fused q/k/v/g projection: Eb[73728x256] @ Wcat^T[1024x256]
__global__ __launch_bounds__(256) void k_proj_mfma(
    const u16* __restrict__ Eb, const u16* __restrict__ Wcat,
    const float* __restrict__ biascat,
    u16* __restrict__ qb, u16* __restrict__ kb,
    u16* __restrict__ vb, u16* __restrict__ gb)
{
    __shared__ u16 As[128*32];
    __shared__ u16 Bs[128*32];
    const int m0 = blockIdx.x*128, n0 = blockIdx.y*128;
    const int t = threadIdx.x, lane = t&63, w = t>>6;
    f32x4 acc[4][4];
    #pragma unroll
    for (int i=0;i<4;i++)
        #pragma unroll
        for (int j=0;j<4;j++) acc[i][j] = f32x4{0.f,0.f,0.f,0.f};
    gemm128_acc(Eb + (size_t)m0*DD, DD, Wcat + (size_t)n0*DD, DD, As, Bs, acc, t);

    const int p = n0 >> 8;                 // uniform per block
    u16* outp = p==0?qb : p==1?kb : p==2?vb : gb;
    const int wm = (w>>1)*64, wn = (w&1)*64;
    #pragma unroll
    for (int mf=0; mf<4; mf++){
        int m = m0 + wm + mf*16 + (lane>>4)*4;
        #pragma unroll
        for (int nf=0; nf<4; nf++){
            int gn = n0 + wn + nf*16 + (lane&15);
            float bias = biascat[gn];
            int col = gn & 255;
            #pragma unroll
            for (int r=0; r<4; r++){
                float v = acc[mf][nf][r] + bias;
                if (p==3) v = 1.0f/(1.0f+__expf(-v));
                outp[(size_t)(m+r)*DD + col] = f2bfu(v);
            }
        }
    }
}

// final: out = relu(hb @ Wob^T + bo), f32
__global__ __launch_bounds__(256) void k_final_mfma(
    const u16* __restrict__ hb, const u16* __restrict__ Wob,
    const float* __restrict__ bo, float* __restrict__ out)
{
    __shared__ u16 As[128*32];
    __shared__ u16 Bs[128*32];
    const int m0 = blockIdx.x*128, n0 = blockIdx.y*128;
    const int t = threadIdx.x, lane = t&63, w = t>>6;
    f32x4 acc[4][4];
    #pragma unroll
    for (int i=0;i<4;i++)
        #pragma unroll
        for (int j=0;j<4;j++) acc[i][j] = f32x4{0.f,0.f,0.f,0.f};
    gemm128_acc(hb + (size_t)m0*DD, DD, Wob + (size_t)n0*DD, DD, As, Bs, acc, t);

    const int wm = (w>>1)*64, wn = (w&1)*64;
    #pragma unroll
    for (int mf=0; mf<4; mf++){
        int m = m0 + wm + mf*16 + (lane>>4)*4;
        #pragma unroll
        for (int nf=0; nf<4; nf++){
            int n = n0 + wn + nf*16 + (lane&15);
            float bias = bo[n];
            #pragma unroll
            for (int r=0; r<4; r++)
                out[(size_t)(m+r)*DD + n] = fmaxf(acc[mf][nf][r] + bias, 0.0f);
        }
    }
}

// ------------------------------------------------------------------
// 64x64 MFMA tile core: 4 waves, each 32x32 = 2x2 frags. Accumulating.
// ------------------------------------------------------------------
template<int KLEN>
static __device__ __forceinline__ void gemm64_acc(
    const u16* __restrict__ A, size_t Ast,
    const u16* __restrict__ B, size_t Bst,
    u16* As, u16* Bs, f32x4 acc[2][2], int t)
{
    const int lane = t & 63, w = t >> 6;
    const int wm = (w>>1)*32, wn = (w&1)*32;
    int offA[2], offB[2];
    #pragma unroll
    for (int f=0; f<2; f++){
        int ra = wm + f*16 + (lane&15);
        offA[f] = ra*32 + (((lane>>4) ^ ((ra>>1)&3)) << 3);
        int rb = wn + f*16 + (lane&15);
        offB[f] = rb*32 + (((lane>>4) ^ ((rb>>1)&3)) << 3);
    }
    const int c = t, row = c>>2, ks = (c&3) ^ ((row>>1)&3);
    const u16* gA = A + (size_t)row*Ast + ks*8;
    const u16* gB = B + (size_t)row*Bst + ks*8;
    for (int k0=0; k0<KLEN; k0+=32){
        gl_lds16(gA + k0, As + c*8);
        gl_lds16(gB + k0, Bs + c*8);
        __syncthreads();
        bf16x8 a[2], b[2];
        #pragma unroll
        for (int f=0; f<2; f++) a[f] = *(const bf16x8*)(As + offA[f]);
        #pragma unroll
        for (int f=0; f<2; f++) b[f] = *(const bf16x8*)(Bs + offB[f]);
        #pragma unroll
        for (int mf=0; mf<2; mf++)
            #pragma unroll
            for (int nf=0; nf<2; nf++)
                acc[mf][nf] = __builtin_amdgcn_mfma_f32_16x16x32_bf16(a[mf], b[nf], acc[mf][nf], 0, 0, 0);
        __syncthreads();
    }
}

// term1[b,i,j,l] = q[b,i,j,:] . k[b,i,l,:]
__global__ __launch_bounds__(256) void k_term1(
    const u16* __restrict__ qb, const u16* __restrict__ kb, float* __restrict__ alpha)
{
    __shared__ u16 As[64*32];
    __shared__ u16 Bs[64*32];
    const int bi = blockIdx.z, j0 = blockIdx.x*64, l0 = blockIdx.y*64;
    const int t = threadIdx.x, lane = t&63, w = t>>6;
    f32x4 acc[2][2];
    #pragma unroll
    for (int i=0;i<2;i++)
        #pragma unroll
        for (int j=0;j<2;j++) acc[i][j] = f32x4{0.f,0.f,0.f,0.f};
    gemm64_acc<DD>(qb + ((size_t)bi*NG + j0)*DD, DD,
                   kb + ((size_t)bi*NG + l0)*DD, DD, As, Bs, acc, t);
    const int wm = (w>>1)*32, wn = (w&1)*32;
    #pragma unroll
    for (int mf=0; mf<2; mf++)
        #pragma unroll
        for (int nf=0; nf<2; nf++)
            #pragma unroll
            for (int r=0; r<4; r++){
                int j = j0 + wm + mf*16 + (lane>>4)*4 + r;
                int l = l0 + wn + nf*16 + (lane&15);
                alpha[((size_t)bi*NG + j)*NG + l] = acc[mf][nf][r];
            }
}

// term2[b,i,j,l] += q[b,i,j,:] . k[b,l,j,:]   batched over (b,j)
__global__ __launch_bounds__(256) void k_term2(
    const u16* __restrict__ qb, const u16* __restrict__ kb, float* __restrict__ alpha)
{
    __shared__ u16 As[64*32];
    __shared__ u16 Bs[64*32];
    const int bj = blockIdx.z, b = bj/NG, j = bj%NG;
    const int i0 = blockIdx.x*64, l0 = blockIdx.y*64;
    const int t = threadIdx.x, lane = t&63, w = t>>6;
    f32x4 acc[2][2];
    #pragma unroll
    for (int i=0;i<2;i++)
        #pragma unroll
        for (int jj=0;jj<2;jj++) acc[i][jj] = f32x4{0.f,0.f,0.f,0.f};
    gemm64_acc<DD>(qb + (((size_t)b*NG + i0)*NG + j)*DD, (size_t)NG*DD,
                   kb + (((size_t)b*NG + l0)*NG + j)*DD, (size_t)NG*DD, As, Bs, acc, t);
    const int wm = (w>>1)*32, wn = (w&1)*32;
    #pragma unroll
    for (int mf=0; mf<2; mf++)
        #pragma unroll
        for (int nf=0; nf<2; nf++)
            #pragma unroll
            for (int r=0; r<4; r++){
                int i = i0 + wm + mf*16 + (lane>>4)*4 + r;
                int l = l0 + wn + nf*16 + (lane&15);
                size_t idx = (((size_t)b*NG + i)*NG + j)*NG + l;
                alpha[idx] += acc[mf][nf][r];
            }
}

// ------------------------------------------------------------------
// softmax over l, scale 1/16, bias bm[b,i,l]+bm[b,l,i]; bf16 out
// ------------------------------------------------------------------
__global__ __launch_bounds__(256) void k_softmax(
    const float* __restrict__ alpha, const float* __restrict__ bm,
    u16* __restrict__ alphab)
{
    int row  = blockIdx.x*4 + (threadIdx.x >> 6);   // (b*NG + i)*NG + j
    int lane = threadIdx.x & 63;
    int b = row / NN2;
    int i = (row / NG) % NG;
    const float* arow = alpha + (size_t)row*NG;
    const float* bmb  = bm + (size_t)b*NN2;
    float vals[3];
    float mx = -1e30f;
    #pragma unroll
    for (int tt=0; tt<3; tt++){
        int l = lane + tt*64;
        float s = arow[l]*0.0625f + bmb[(size_t)i*NG + l] + bmb[(size_t)l*NG + i];
        vals[tt] = s;
        mx = fmaxf(mx, s);
    }
    #pragma unroll
    for (int off=32; off; off>>=1) mx = fmaxf(mx, __shfl_xor(mx, off));
    float sum = 0.f;
    #pragma unroll
    for (int tt=0; tt<3; tt++){ vals[tt] = __expf(vals[tt]-mx); sum += vals[tt]; }
    #pragma unroll
    for (int off=32; off; off>>=1) sum += __shfl_xor(sum, off);
    float inv = 1.0f/sum;
    #pragma unroll
    for (int tt=0; tt<3; tt++) alphab[(size_t)row*NG + lane + tt*64] = f2bfu(vals[tt]*inv);
}

// ------------------------------------------------------------------
// bmat GEMV (f32 E): bm[m] = E[m,:] . Wb + bb
// ------------------------------------------------------------------
__global__ __launch_bounds__(256) void k_bmat(
    const float* __restrict__ E, const float* __restrict__ Wb,
    const float* __restrict__ bb, float* __restrict__ bm)
{
    int row  = blockIdx.x*4 + (threadIdx.x >> 6);
    int lane = threadIdx.x & 63;
    float4 e = ((const float4*)(E + (size_t)row*DD))[lane];
    float4 w = ((const float4*)Wb)[lane];
    float s = e.x*w.x + e.y*w.y + e.z*w.z + e.w*w.w;
    #pragma unroll
    for (int off=32; off; off>>=1) s += __shfl_down(s, off);
    if (lane==0) bm[row] = s + bb[0];
}

// ------------------------------------------------------------------
// V transposes: vT1[b,i,d,l] = v[b,i,l,d]; vT2[b,i,d,l] = v[b,l,i,d]
// ------------------------------------------------------------------
__global__ __launch_bounds__(256) void k_vtrans(
    const u16* __restrict__ vb, u16* __restrict__ vT1, u16* __restrict__ vT2)
{
    __shared__ u16 tile[64][72];
    const int z = blockIdx.z, which = z & 1, bi = z >> 1;
    const int b = bi/NG, i = bi%NG;
    const int l0 = blockIdx.x*64, d0 = blockIdx.y*64;
    const u16* src; size_t rstride;
    if (which == 0){ src = vb + ((size_t)bi*NG + l0)*DD + d0;               rstride = DD; }
    else           { src = vb + (((size_t)b*NG + l0)*NG + i)*DD + d0;       rstride = (size_t)NG*DD; }
    const int t = threadIdx.x;
    const int r = t >> 2, cs = (t&3)*16;
    #pragma unroll
    for (int q=0; q<4; q++)
        *(ushort4*)&tile[r][cs + q*4] = *(const ushort4*)(src + (size_t)r*rstride + cs + q*4);
    __syncthreads();
    u16* dst = (which ? vT2 : vT1) + ((size_t)bi*DD + d0 + r)*NG + l0 + cs;
    #pragma unroll
    for (int q=0; q<4; q++){
        ushort4 y;
        y.x = tile[cs+q*4+0][r];
        y.y = tile[cs+q*4+1][r];
        y.z = tile[cs+q*4+2][r];
        y.w = tile[cs+q*4+3][r];
        *(ushort4*)(dst + q*4) = y;
    }
}

// ------------------------------------------------------------------
// attnout: h = g * (A1 @ vT1^T + A2 @ vT2^T) per (b,i)
// ------------------------------------------------------------------
__global__ __launch_bounds__(256) void k_attnout(
    const u16* __restrict__ alphab, const u16* __restrict__ vT1,
    const u16* __restrict__ vT2, const u16* __restrict__ gb,
    u16* __restrict__ hb)
{
    __shared__ u16 As[64*32];
    __shared__ u16 Bs[64*32];
    const int bi = blockIdx.z, b = bi/NG, i = bi%NG;
    const int j0 = blockIdx.x*64, d0 = blockIdx.y*64;
    const int t = threadIdx.x, lane = t&63, w = t>>6;
    f32x4 acc[2][2];
    #pragma unroll
    for (int ii=0;ii<2;ii++)
        #pragma unroll
        for (int jj=0;jj<2;jj++) acc[ii][jj] = f32x4{0.f,0.f,0.f,0.f};
    gemm64_acc<NG>(alphab + ((size_t)bi*NG + j0)*NG, NG,
                   vT1 + ((size_t)bi*DD + d0)*NG, NG, As, Bs, acc, t);
    gemm64_acc<NG>(alphab + (((size_t)(b*NG + j0))*NG + i)*NG, (size_t)NN2,
                   vT2 + ((size_t)bi*DD + d0)*NG, NG, As, Bs, acc, t);
    const int wm = (w>>1)*32, wn = (w&1)*32;
    #pragma unroll
    for (int mf=0; mf<2; mf++)
        #pragma unroll
        for (int nf=0; nf<2; nf++)
            #pragma unroll
            for (int r=0; r<4; r++){
                int j = j0 + wm + mf*16 + (lane>>4)*4 + r;
                int d = d0 + wn + nf*16 + (lane&15);
                size_t idx = ((size_t)bi*NG + j)*DD + d;
                hb[idx] = f2bfu(bfu2f(gb[idx]) * acc[mf][nf][r]);
            }
}

// ------------------------------------------------------------------
// Workspace overlays (total 208.6 MB, vs round-1's proven 207.9 MB):
//   [0,        56.6M) : alpha f32      | Eb bf16 (dead after proj)  | vT2 (after softmax)
//   [56.6M,    94.4M) : qb             | alphab (after term2)
//   [94.4M,   132.1M) : kb             | vT1 (after term2)
//   [132.1M,  169.9M) : vb             | hb (after vtrans)
//   [169.9M,  207.6M) : gb
//   [207.6M,  208.6M) : bm, Wcat, Wob, biascat
// ------------------------------------------------------------------
extern "C" void kernel_launch(void* const* d_in, const int* in_sizes, int n_in,
                              void* d_out, int out_size, void* d_ws, size_t ws_size,
                              hipStream_t stream)
{
    const float* E  = (const float*)d_in[0];
    const float* Wq = (const float*)d_in[1];  const float* bq = (const float*)d_in[2];
    const float* Wk = (const float*)d_in[3];  const float* bk = (const float*)d_in[4];
    const float* Wv = (const float*)d_in[5];  const float* bv = (const float*)d_in[6];
    const float* Wb = (const float*)d_in[7];  const float* bb = (const float*)d_in[8];
    const float* Wg = (const float*)d_in[9];  const float* bg = (const float*)d_in[10];
    const float* Wo = (const float*)d_in[11]; const float* bo = (const float*)d_in[12];
    float* out = (float*)d_out;

    const size_t BF = (size_t)MT*DD*2;          // 37,748,736 B
    char* ws = (char*)d_ws;
    size_t off = 0;
    float* alpha = (float*)(ws+off);            // 56,623,104 B
    u16*   Eb    = (u16*)(ws+off);              //   overlay (dead after proj)
    u16*   vT2   = (u16*)(ws+off);              //   overlay (written after softmax)
    off += (size_t)NB*NG*NG*NG*4;
    u16* qb     = (u16*)(ws+off);
    u16* alphab = (u16*)(ws+off);               //   overlay (q dead after term2)
    off += BF;
    u16* kb  = (u16*)(ws+off);
    u16* vT1 = (u16*)(ws+off);                  //   overlay (k dead after term2)
    off += BF;
    u16* vb = (u16*)(ws+off);
    u16* hb = (u16*)(ws+off);                   //   overlay (v dead after vtrans)
    off += BF;
    u16* gb = (u16*)(ws+off); off += BF;
    float* bm    = (float*)(ws+off); off += (size_t)MT*4;
    u16* Wcat    = (u16*)(ws+off);   off += (size_t)1024*DD*2;
    u16* Wob     = (u16*)(ws+off);   off += (size_t)DD*DD*2;
    float* biascat = (float*)(ws+off); off += 1024*4;
    (void)ws_size;

    k_cast_w   <<<dim3(256), 256, 0, stream>>>(Wq,Wk,Wv,Wg,Wo, bq,bk,bv,bg, Wcat, Wob, biascat);
    k_cast_e   <<<dim3(9216), 256, 0, stream>>>(E, Eb);
    k_proj_mfma<<<dim3(MT/128, 8), 256, 0, stream>>>(Eb, Wcat, biascat, qb, kb, vb, gb);
    k_bmat     <<<dim3(MT/4), 256, 0, stream>>>(E, Wb, bb, bm);
    k_term1    <<<dim3(NG/64, NG/64, NB*NG), 256, 0, stream>>>(qb, kb, alpha);
    k_term2    <<<dim3(NG/64, NG/64, NB*NG), 256, 0, stream>>>(qb, kb, alpha);
    k_softmax  <<<dim3(MT/4), 256, 0, stream>>>(alpha, bm, alphab);
    k_vtrans   <<<dim3(NG/64, DD/64, NB*NG*2), 256, 0, stream>>>(vb, vT1, vT2);
    k_attnout  <<<dim3(NG/64, DD/64, NB*NG), 256, 0, stream>>>(alphab, vT1, vT2, gb, hb);
    k_final_mfma<<<dim3(MT/128, DD/128), 256, 0, stream>>>(hb, Wob, bo, out);
}

// Round 4
// 278.476 us; speedup vs baseline: 5.6409x; 1.5101x over previous
//
#include <hip/hip_runtime.h>
#include <hip/hip_bf16.h>

typedef __hip_bfloat16 bf16;
typedef unsigned short u16;
typedef __attribute__((ext_vector_type(8))) short bf16x8;
typedef __attribute__((ext_vector_type(4))) float f32x4;

#define NB   2
#define NG   192
#define DD   256
#define NN2  (NG*NG)          // 36864
#define MT   (NB*NN2)         // 73728

static __device__ __forceinline__ float bfu2f(u16 u){
    return __uint_as_float(((unsigned)u) << 16);
}
static __device__ __forceinline__ u16 f2bfu(float f){
    bf16 h = __float2bfloat16(f);
    return *(u16*)&h;
}

// async global->LDS, 16B/lane. LDS dest: wave-uniform base + lane*16 (linear).
static __device__ __forceinline__ void gl_lds16(const void* g, void* l){
    __builtin_amdgcn_global_load_lds(
        (const __attribute__((address_space(1))) unsigned int*)g,
        (__attribute__((address_space(3))) unsigned int*)l, 16, 0, 0);
}
// XOR swizzle (already shifted to bits 3-5 of an element index)
static __device__ __forceinline__ int swz3(int x){ return ((x ^ (x>>3)) & 7) << 3; }

// ------------------------------------------------------------------
// casts
// ------------------------------------------------------------------
__global__ __launch_bounds__(256) void k_cast_e(const float* __restrict__ E, u16* __restrict__ Eb){
    size_t i = ((size_t)blockIdx.x*256 + threadIdx.x)*8;
    float4 x = *(const float4*)(E+i);
    float4 y = *(const float4*)(E+i+4);
    ushort4 a; a.x=f2bfu(x.x); a.y=f2bfu(x.y); a.z=f2bfu(x.z); a.w=f2bfu(x.w);
    ushort4 b; b.x=f2bfu(y.x); b.y=f2bfu(y.y); b.z=f2bfu(y.z); b.w=f2bfu(y.w);
    *(ushort4*)(Eb+i)   = a;
    *(ushort4*)(Eb+i+4) = b;
}

__global__ __launch_bounds__(256) void k_cast_w(
    const float* __restrict__ Wq, const float* __restrict__ Wk,
    const float* __restrict__ Wv, const float* __restrict__ Wg,
    const float* __restrict__ Wo, const float* __restrict__ Wb,
    const float* __restrict__ bq, const float* __restrict__ bk,
    const float* __restrict__ bv, const float* __restrict__ bg,
    u16* __restrict__ Wcat, u16* __restrict__ Wob, u16* __restrict__ Wbb,
    float* __restrict__ biascat)
{
    int e = blockIdx.x*256 + threadIdx.x;      // 65536 total
    Wcat[e]          = f2bfu(Wq[e]);
    Wcat[65536 + e]  = f2bfu(Wk[e]);
    Wcat[131072 + e] = f2bfu(Wv[e]);
    Wcat[196608 + e] = f2bfu(Wg[e]);
    Wob[e]           = f2bfu(Wo[e]);
    if (e < 256) Wbb[e] = f2bfu(Wb[e]);
    if (e < 1024){
        int p = e>>8, r = e&255;
        const float* bp = p==0?bq : p==1?bk : p==2?bv : bg;
        biascat[e] = bp[r];
    }
}

// ------------------------------------------------------------------
// 128x128 MFMA tile core (K=256): C = A(128xK) . B(128xK)^T  (proven r3)
// ------------------------------------------------------------------
static __device__ __forceinline__ void gemm128_acc(
    const u16* __restrict__ A, size_t Ast,
    const u16* __restrict__ B, size_t Bst,
    u16* As, u16* Bs, f32x4 acc[4][4], int t)
{
    const int lane = t & 63, w = t >> 6;
    const int wm = (w>>1)*64, wn = (w&1)*64;
    int offA[4], offB[4];
    #pragma unroll
    for (int f=0; f<4; f++){
        int ra = wm + f*16 + (lane&15);
        offA[f] = ra*32 + (((lane>>4) ^ ((ra>>1)&3)) << 3);
        int rb = wn + f*16 + (lane&15);
        offB[f] = rb*32 + (((lane>>4) ^ ((rb>>1)&3)) << 3);
    }
    for (int k0=0; k0<DD; k0+=32){
        #pragma unroll
        for (int it=0; it<2; it++){
            int c = it*256 + t;
            int row = c >> 2;
            int ks  = (c&3) ^ ((row>>1)&3);
            gl_lds16(A + (size_t)row*Ast + k0 + ks*8, As + c*8);
            gl_lds16(B + (size_t)row*Bst + k0 + ks*8, Bs + c*8);
        }
        __syncthreads();
        bf16x8 a[4], b[4];
        #pragma unroll
        for (int f=0; f<4; f++) a[f] = *(const bf16x8*)(As + offA[f]);
        #pragma unroll
        for (int f=0; f<4; f++) b[f] = *(const bf16x8*)(Bs + offB[f]);
        #pragma unroll
        for (int mf=0; mf<4; mf++)
            #pragma unroll
            for (int nf=0; nf<4; nf++)
                acc[mf][nf] = __builtin_amdgcn_mfma_f32_16x16x32_bf16(a[mf], b[nf], acc[mf][nf], 0, 0, 0);
        __syncthreads();
    }
}

// fused q/k/v/g projection: Eb[73728x256] @ Wcat^T[1024x256]
__global__ __launch_bounds__(256) void k_proj_mfma(
    const u16* __restrict__ Eb, const u16* __restrict__ Wcat,
    const float* __restrict__ biascat,
    u16* __restrict__ qb, u16* __restrict__ kb,
    u16* __restrict__ vb, u16* __restrict__ gb)
{
    __shared__ u16 As[128*32];
    __shared__ u16 Bs[128*32];
    const int m0 = blockIdx.x*128, n0 = blockIdx.y*128;
    const int t = threadIdx.x, lane = t&63, w = t>>6;
    f32x4 acc[4][4];
    #pragma unroll
    for (int i=0;i<4;i++)
        #pragma unroll
        for (int j=0;j<4;j++) acc[i][j] = f32x4{0.f,0.f,0.f,0.f};
    gemm128_acc(Eb + (size_t)m0*DD, DD, Wcat + (size_t)n0*DD, DD, As, Bs, acc, t);

    const int p = n0 >> 8;
    u16* outp = p==0?qb : p==1?kb : p==2?vb : gb;
    const int wm = (w>>1)*64, wn = (w&1)*64;
    #pragma unroll
    for (int mf=0; mf<4; mf++){
        int m = m0 + wm + mf*16 + (lane>>4)*4;
        #pragma unroll
        for (int nf=0; nf<4; nf++){
            int gn = n0 + wn + nf*16 + (lane&15);
            float bias = biascat[gn];
            int col = gn & 255;
            #pragma unroll
            for (int r=0; r<4; r++){
                float v = acc[mf][nf][r] + bias;
                if (p==3) v = 1.0f/(1.0f+__expf(-v));
                outp[(size_t)(m+r)*DD + col] = f2bfu(v);
            }
        }
    }
}

// final: out = relu(hb @ Wob^T + bo), f32
__global__ __launch_bounds__(256) void k_final_mfma(
    const u16* __restrict__ hb, const u16* __restrict__ Wob,
    const float* __restrict__ bo, float* __restrict__ out)
{
    __shared__ u16 As[128*32];
    __shared__ u16 Bs[128*32];
    const int m0 = blockIdx.x*128, n0 = blockIdx.y*128;
    const int t = threadIdx.x, lane = t&63, w = t>>6;
    f32x4 acc[4][4];
    #pragma unroll
    for (int i=0;i<4;i++)
        #pragma unroll
        for (int j=0;j<4;j++) acc[i][j] = f32x4{0.f,0.f,0.f,0.f};
    gemm128_acc(hb + (size_t)m0*DD, DD, Wob + (size_t)n0*DD, DD, As, Bs, acc, t);

    const int wm = (w>>1)*64, wn = (w&1)*64;
    #pragma unroll
    for (int mf=0; mf<4; mf++){
        int m = m0 + wm + mf*16 + (lane>>4)*4;
        #pragma unroll
        for (int nf=0; nf<4; nf++){
            int n = n0 + wn + nf*16 + (lane&15);
            float bias = bo[n];
            #pragma unroll
            for (int r=0; r<4; r++)
                out[(size_t)(m+r)*DD + n] = fmaxf(acc[mf][nf][r] + bias, 0.0f);
        }
    }
}

// ------------------------------------------------------------------
// bmat GEMV (bf16): bm[m] = Eb[m,:] . Wbb + bb; 8 rows/block
// ------------------------------------------------------------------
__global__ __launch_bounds__(256) void k_bmat(
    const u16* __restrict__ Eb, const u16* __restrict__ Wbb,
    const float* __restrict__ bb, float* __restrict__ bm)
{
    int row = blockIdx.x*8 + (threadIdx.x >> 5);
    int l32 = threadIdx.x & 31;
    const u16* er = Eb + (size_t)row*DD + l32*8;
    const u16* wr = Wbb + l32*8;
    float s = 0.f;
    #pragma unroll
    for (int q=0; q<8; q++) s += bfu2f(er[q]) * bfu2f(wr[q]);
    #pragma unroll
    for (int off=16; off; off>>=1) s += __shfl_xor(s, off);
    if (l32 == 0) bm[row] = s + bb[0];
}

// biassym[b,i,l] = bm[b,i,l] + bm[b,l,i]
__global__ __launch_bounds__(256) void k_bias_sym(
    const float* __restrict__ bm, float* __restrict__ biassym)
{
    int rem = blockIdx.x*256 + threadIdx.x;     // < 36864
    int b = blockIdx.y;
    int i = rem / NG, l = rem % NG;
    biassym[(size_t)b*NN2 + rem] = bm[(size_t)b*NN2 + rem] + bm[(size_t)b*NN2 + l*NG + i];
}

// ------------------------------------------------------------------
// scores: 192x192x256 GEMM per block.
// MODE 0 (t1): block (b, i=r): S[j,l] = q[b,i,j,:].k[b,i,l,:]*1/16 + biassym[b,i,l]
// MODE 1 (t2): block (b, j=r): S[i,l] += q[b,i,j,:].k[b,l,j,:]*1/16   (RMW)
// 8 waves (4m x 2n), acc 3x6, K-step 64, double-buffered gl_lds,
// counted vmcnt + raw s_barrier (no __syncthreads drain).
// ------------------------------------------------------------------
template<int MODE>
__global__ __launch_bounds__(512, 2) void k_scores(
    const u16* __restrict__ q, const u16* __restrict__ kmat,
    const float* __restrict__ biassym, float* __restrict__ scores)
{
    __shared__ u16 As[2][NG*64];
    __shared__ u16 Bs[2][NG*64];
    const int z = blockIdx.x, b = z/NG, r = z%NG;
    const int t = threadIdx.x, lane = t&63, w = t>>6;
    const int wm = (w&3)*48, wn = (w>>2)*96;
    const size_t astr = MODE ? (size_t)NG*DD : (size_t)DD;
    const u16* Ab = MODE ? q    + ((size_t)b*NN2 + r)*DD : q    + ((size_t)b*NG + r)*NG*DD;
    const u16* Bb = MODE ? kmat + ((size_t)b*NN2 + r)*DD : kmat + ((size_t)b*NG + r)*NG*DD;

    f32x4 acc[3][6];
    #pragma unroll
    for (int i=0;i<3;i++)
        #pragma unroll
        for (int j=0;j<6;j++) acc[i][j] = f32x4{0.f,0.f,0.f,0.f};

    int offA[3], offB[6];
    #pragma unroll
    for (int mf=0; mf<3; mf++){
        int x = wm + mf*16 + (lane&15);
        offA[mf] = x*64 + (((lane>>4)<<3) ^ swz3(x));
    }
    #pragma unroll
    for (int nf=0; nf<6; nf++){
        int x = wn + nf*16 + (lane&15);
        offB[nf] = x*64 + (((lane>>4)<<3) ^ swz3(x));
    }

    auto stage = [&](int buf, int k0){
        #pragma unroll
        for (int rr=0; rr<3; rr++){
            int c = t + rr*512;
            int x = c>>3, l8e = (c&7)<<3;
            size_t ro = (size_t)x*astr + k0;
            gl_lds16(Ab + ro + (l8e ^ swz3(x)), &As[buf][c*8]);
            gl_lds16(Bb + ro + (l8e ^ swz3(x)), &Bs[buf][c*8]);
        }
    };

    stage(0, 0);
    for (int ks=0; ks<4; ks++){
        if (ks<3){
            stage((ks+1)&1, (ks+1)*64);
            asm volatile("s_waitcnt vmcnt(6)" ::: "memory");
        } else {
            asm volatile("s_waitcnt vmcnt(0)" ::: "memory");
        }
        __builtin_amdgcn_s_barrier();
        const u16* A = &As[ks&1][0];
        const u16* B = &Bs[ks&1][0];
        #pragma unroll
        for (int kk=0; kk<2; kk++){
            bf16x8 a[3];
            #pragma unroll
            for (int mf=0; mf<3; mf++) a[mf] = *(const bf16x8*)(A + (offA[mf]^(kk<<5)));
            #pragma unroll
            for (int nf=0; nf<6; nf++){
                bf16x8 bf = *(const bf16x8*)(B + (offB[nf]^(kk<<5)));
                #pragma unroll
                for (int mf=0; mf<3; mf++)
                    acc[mf][nf] = __builtin_amdgcn_mfma_f32_16x16x32_bf16(a[mf], bf, acc[mf][nf], 0, 0, 0);
            }
        }
        __builtin_amdgcn_s_barrier();
    }

    const size_t base_b = (size_t)b*NN2*NG;
    #pragma unroll
    for (int mf=0; mf<3; mf++){
        #pragma unroll
        for (int nf=0; nf<6; nf++){
            int lcol = wn + nf*16 + (lane&15);
            float bias = MODE ? 0.f : biassym[((size_t)b*NG + r)*NG + lcol];
            #pragma unroll
            for (int r4=0; r4<4; r4++){
                int x = wm + mf*16 + (lane>>4)*4 + r4;   // j (M0) or i (M1)
                size_t idx = MODE ? base_b + ((size_t)x*NG + r)*NG + lcol
                                  : base_b + ((size_t)r*NG + x)*NG + lcol;
                float v = acc[mf][nf][r4]*0.0625f;
                if (MODE) scores[idx] += v;
                else      scores[idx] = v + bias;
            }
        }
    }
}

// ------------------------------------------------------------------
// softmax over l; writes bf16 alpha[b,i,j,:] and alphaT[b,j,i,:]
// ------------------------------------------------------------------
__global__ __launch_bounds__(256) void k_softmax(
    const float* __restrict__ scores, u16* __restrict__ alpha, u16* __restrict__ alphaT)
{
    int rr   = blockIdx.x*4 + (threadIdx.x >> 6);   // i*NG + j
    int lane = threadIdx.x & 63;
    int b = blockIdx.y;
    int i = rr / NG, j = rr % NG;
    const float* arow = scores + ((size_t)b*NN2 + rr)*NG;
    float vals[3];
    float mx = -1e30f;
    #pragma unroll
    for (int tt=0; tt<3; tt++){
        float s = arow[lane + tt*64];
        vals[tt] = s;
        mx = fmaxf(mx, s);
    }
    #pragma unroll
    for (int off=32; off; off>>=1) mx = fmaxf(mx, __shfl_xor(mx, off));
    float sum = 0.f;
    #pragma unroll
    for (int tt=0; tt<3; tt++){ vals[tt] = __expf(vals[tt]-mx); sum += vals[tt]; }
    #pragma unroll
    for (int off=32; off; off>>=1) sum += __shfl_xor(sum, off);
    float inv = 1.0f/sum;
    u16* arow1 = alpha  + ((size_t)b*NN2 + rr)*NG;
    u16* arow2 = alphaT + ((size_t)b*NN2 + (size_t)j*NG + i)*NG;
    #pragma unroll
    for (int tt=0; tt<3; tt++){
        u16 vq = f2bfu(vals[tt]*inv);
        arow1[lane + tt*64] = vq;
        arow2[lane + tt*64] = vq;
    }
}

// ------------------------------------------------------------------
// attnout: block (bi, dhalf): out[192 j x 128 d] = A1@V1^T + A2@V2^T, gated.
// A via dbuf gl_lds (pre-swizzled source); V transposed in-kernel
// (reg-staged, b16 scatter, double-XOR swizzle s(d)=(d^(d>>3))&7).
// ------------------------------------------------------------------
__global__ __launch_bounds__(512, 4) void k_attnout(
    const u16* __restrict__ alpha, const u16* __restrict__ alphaT,
    const u16* __restrict__ vb, const u16* __restrict__ gb, u16* __restrict__ hb)
{
    __shared__ u16 AsL[2][NG*64];    // 2 x 24.0 KiB
    __shared__ u16 Vs[128*64];       // 16 KiB
    const int z = blockIdx.x, bi = z>>1, dh = z&1;
    const int b = bi/NG, i = bi%NG;
    const int dbase = dh*128;
    const int t = threadIdx.x, lane = t&63, w = t>>6;
    const int wm = (w&1)*96, wn = (w>>1)*32;

    const u16* Abase0 = alpha  + (size_t)bi*NN2;
    const u16* Abase1 = alphaT + (size_t)bi*NN2;
    const u16* V0 = vb + (size_t)bi*NG*DD + dbase;             // + l*DD
    const u16* V1 = vb + ((size_t)b*NG*NG + i)*DD + dbase;     // + l*NG*DD

    f32x4 acc[6][2];
    #pragma unroll
    for (int m=0;m<6;m++)
        #pragma unroll
        for (int n=0;n<2;n++) acc[m][n] = f32x4{0.f,0.f,0.f,0.f};

    int offA[6], offB[2];
    #pragma unroll
    for (int mf=0; mf<6; mf++){
        int j = wm + mf*16 + (lane&15);
        offA[mf] = j*64 + (((lane>>4)<<3) ^ swz3(j));
    }
    #pragma unroll
    for (int nf=0; nf<2; nf++){
        int d = wn + nf*16 + (lane&15);
        offB[nf] = d*64 + (((lane>>4)<<3) ^ swz3(d));
    }

    int4 vr[2];
    auto stageA = [&](int u, int buf){
        const u16* Ab = (u>=3) ? Abase1 : Abase0;
        int ls = (u>=3 ? u-3 : u)*64;
        #pragma unroll
        for (int rr=0; rr<3; rr++){
            int c = t + rr*512;
            int j = c>>3, l8e = (c&7)<<3;
            gl_lds16(Ab + (size_t)j*NG + ls + (l8e ^ swz3(j)), &AsL[buf][c*8]);
        }
    };
    auto loadV = [&](int u){
        int p = (u>=3), ls = (u>=3 ? u-3 : u)*64;
        #pragma unroll
        for (int rr=0; rr<2; rr++){
            int c = t + rr*512;
            int l = ls + (c>>4), d0 = (c&15)*8;
            const u16* src = p ? (V1 + (size_t)l*NG*DD + d0) : (V0 + (size_t)l*DD + d0);
            vr[rr] = *(const int4*)src;
        }
    };

    stageA(0, 0);
    loadV(0);
    for (int u=0; u<6; u++){
        // transpose-write V(u) into Vs[d][l] (swizzled)
        #pragma unroll
        for (int rr=0; rr<2; rr++){
            int c = t + rr*512;
            int l = c>>4;
            l &= 63;
            int d0 = (c&15)*8, c3 = c&7;
            ushort* vp = (ushort*)&vr[rr];
            #pragma unroll
            for (int qd=0; qd<8; qd++)
                Vs[(d0+qd)*64 + (l ^ ((qd^c3)<<3))] = vp[qd];
        }
        if (u<5){ stageA(u+1, (u+1)&1); loadV(u+1); }
        asm volatile("s_waitcnt lgkmcnt(0)" ::: "memory");
        __builtin_amdgcn_s_barrier();
        const u16* A = &AsL[u&1][0];
        #pragma unroll
        for (int kk=0; kk<2; kk++){
            bf16x8 bfr[2];
            #pragma unroll
            for (int nf=0; nf<2; nf++) bfr[nf] = *(const bf16x8*)(Vs + (offB[nf]^(kk<<5)));
            #pragma unroll
            for (int mf=0; mf<6; mf++){
                bf16x8 afr = *(const bf16x8*)(A + (offA[mf]^(kk<<5)));
                acc[mf][0] = __builtin_amdgcn_mfma_f32_16x16x32_bf16(afr, bfr[0], acc[mf][0], 0, 0, 0);
                acc[mf][1] = __builtin_amdgcn_mfma_f32_16x16x32_bf16(afr, bfr[1], acc[mf][1], 0, 0, 0);
            }
        }
        __builtin_amdgcn_s_barrier();
    }

    #pragma unroll
    for (int mf=0; mf<6; mf++){
        #pragma unroll
        for (int nf=0; nf<2; nf++){
            #pragma unroll
            for (int r4=0; r4<4; r4++){
                int j = wm + mf*16 + (lane>>4)*4 + r4;
                int d = dbase + wn + nf*16 + (lane&15);
                size_t idx = ((size_t)bi*NG + j)*DD + d;
                hb[idx] = f2bfu(bfu2f(gb[idx]) * acc[mf][nf][r4]);
            }
        }
    }
}

// ------------------------------------------------------------------
// Workspace (total ~208.9 MB, round-3-proven level):
//  A [0, 56.6M): Eb (dead after bmat) -> scores f32 (dead after softmax) -> hb
//  B [56.6, 94.4M): qb -> alpha   (after t2)
//  C [94.4, 132.1M): kb -> alphaT (after t2)
//  D [132.1, 169.9M): vb   (live through attnout)
//  E [169.9, 207.6M): gb   (live through attnout)
//  tail: bm, biassym, Wcat, Wob, Wbb, biascat
// ------------------------------------------------------------------
extern "C" void kernel_launch(void* const* d_in, const int* in_sizes, int n_in,
                              void* d_out, int out_size, void* d_ws, size_t ws_size,
                              hipStream_t stream)
{
    const float* E  = (const float*)d_in[0];
    const float* Wq = (const float*)d_in[1];  const float* bq = (const float*)d_in[2];
    const float* Wk = (const float*)d_in[3];  const float* bk = (const float*)d_in[4];
    const float* Wv = (const float*)d_in[5];  const float* bv = (const float*)d_in[6];
    const float* Wb = (const float*)d_in[7];  const float* bb = (const float*)d_in[8];
    const float* Wg = (const float*)d_in[9];  const float* bg = (const float*)d_in[10];
    const float* Wo = (const float*)d_in[11]; const float* bo = (const float*)d_in[12];
    float* out = (float*)d_out;

    const size_t BF = (size_t)MT*DD*2;              // 37,748,736
    const size_t SC = (size_t)NB*NG*NG*NG*4;        // 56,623,104
    char* ws = (char*)d_ws;
    float* scores = (float*)ws;
    u16*   Eb     = (u16*)ws;
    u16*   hb     = (u16*)ws;
    u16* qb = (u16*)(ws + SC);           u16* alpha  = qb;
    u16* kb = (u16*)(ws + SC + BF);      u16* alphaT = kb;
    u16* vb = (u16*)(ws + SC + 2*BF);
    u16* gb = (u16*)(ws + SC + 3*BF);
    size_t tail = SC + 4*BF;
    float* bm      = (float*)(ws + tail); tail += (size_t)MT*4;
    float* biassym = (float*)(ws + tail); tail += (size_t)MT*4;
    u16* Wcat      = (u16*)(ws + tail);   tail += (size_t)1024*DD*2;
    u16* Wob       = (u16*)(ws + tail);   tail += (size_t)DD*DD*2;
    u16* Wbb       = (u16*)(ws + tail);   tail += (size_t)DD*2;
    float* biascat = (float*)(ws + tail); tail += 1024*4;
    (void)ws_size;

    k_cast_w   <<<dim3(256), 256, 0, stream>>>(Wq,Wk,Wv,Wg,Wo,Wb, bq,bk,bv,bg, Wcat, Wob, Wbb, biascat);
    k_cast_e   <<<dim3(9216), 256, 0, stream>>>(E, Eb);
    k_proj_mfma<<<dim3(MT/128, 8), 256, 0, stream>>>(Eb, Wcat, biascat, qb, kb, vb, gb);
    k_bmat     <<<dim3(MT/8), 256, 0, stream>>>(Eb, Wbb, bb, bm);
    k_bias_sym <<<dim3(NN2/256, NB), 256, 0, stream>>>(bm, biassym);
    k_scores<0><<<dim3(NB*NG), 512, 0, stream>>>(qb, kb, biassym, scores);
    k_scores<1><<<dim3(NB*NG), 512, 0, stream>>>(qb, kb, biassym, scores);
    k_softmax  <<<dim3(NN2/4, NB), 256, 0, stream>>>(scores, alpha, alphaT);
    k_attnout  <<<dim3(NB*NG*2), 512, 0, stream>>>(alpha, alphaT, vb, gb, hb);
    k_final_mfma<<<dim3(MT/128, DD/128), 256, 0, stream>>>(hb, Wob, bo, out);
}

// Round 5
// 237.850 us; speedup vs baseline: 6.6044x; 1.1708x over previous
//
#include <hip/hip_runtime.h>
#include <hip/hip_bf16.h>

typedef __hip_bfloat16 bf16;
typedef unsigned short u16;
typedef __attribute__((ext_vector_type(8))) short bf16x8;
typedef __attribute__((ext_vector_type(4))) float f32x4;

#define NB   2
#define NG   192
#define DD   256
#define NN2  (NG*NG)          // 36864
#define MT   (NB*NN2)         // 73728

static __device__ __forceinline__ float bfu2f(u16 u){
    return __uint_as_float(((unsigned)u) << 16);
}
static __device__ __forceinline__ u16 f2bfu(float f){
    bf16 h = __float2bfloat16(f);
    return *(u16*)&h;
}

// async global->LDS, 16B/lane. LDS dest: wave-uniform base + lane*16 (linear).
static __device__ __forceinline__ void gl_lds16(const void* g, void* l){
    __builtin_amdgcn_global_load_lds(
        (const __attribute__((address_space(1))) unsigned int*)g,
        (__attribute__((address_space(3))) unsigned int*)l, 16, 0, 0);
}
// XOR swizzle (element-index bits 3-5)
static __device__ __forceinline__ int swz3(int x){ return ((x ^ (x>>3)) & 7) << 3; }

// ------------------------------------------------------------------
// cast E -> bf16, fused with bmat GEMV: bm[m] = E[m,:].Wb + bb
// block = 2048 elems = 8 rows; 32 threads per row
// ------------------------------------------------------------------
__global__ __launch_bounds__(256) void k_cast_eb(
    const float* __restrict__ E, const float* __restrict__ Wb,
    const float* __restrict__ bb, u16* __restrict__ Eb, float* __restrict__ bm)
{
    const int t = threadIdx.x;
    size_t base = (size_t)blockIdx.x*2048 + t*8;
    float4 x = *(const float4*)(E+base);
    float4 y = *(const float4*)(E+base+4);
    ushort4 a; a.x=f2bfu(x.x); a.y=f2bfu(x.y); a.z=f2bfu(x.z); a.w=f2bfu(x.w);
    ushort4 b; b.x=f2bfu(y.x); b.y=f2bfu(y.y); b.z=f2bfu(y.z); b.w=f2bfu(y.w);
    *(ushort4*)(Eb+base)   = a;
    *(ushort4*)(Eb+base+4) = b;
    const int l32 = t & 31;
    float4 w0 = ((const float4*)Wb)[l32*2];
    float4 w1 = ((const float4*)Wb)[l32*2+1];
    float s = x.x*w0.x + x.y*w0.y + x.z*w0.z + x.w*w0.w
            + y.x*w1.x + y.y*w1.y + y.z*w1.z + y.w*w1.w;
    #pragma unroll
    for (int off=1; off<32; off<<=1) s += __shfl_xor(s, off);
    if (l32 == 0) bm[blockIdx.x*8 + (t>>5)] = s + bb[0];
}

__global__ __launch_bounds__(256) void k_cast_w(
    const float* __restrict__ Wq, const float* __restrict__ Wk,
    const float* __restrict__ Wv, const float* __restrict__ Wg,
    const float* __restrict__ Wo,
    const float* __restrict__ bq, const float* __restrict__ bk,
    const float* __restrict__ bv, const float* __restrict__ bg,
    u16* __restrict__ Wcat, u16* __restrict__ Wob, float* __restrict__ biascat)
{
    int e = blockIdx.x*256 + threadIdx.x;      // 65536 total
    Wcat[e]          = f2bfu(Wq[e]);
    Wcat[65536 + e]  = f2bfu(Wk[e]);
    Wcat[131072 + e] = f2bfu(Wv[e]);
    Wcat[196608 + e] = f2bfu(Wg[e]);
    Wob[e]           = f2bfu(Wo[e]);
    if (e < 1024){
        int p = e>>8, r = e&255;
        const float* bp = p==0?bq : p==1?bk : p==2?bv : bg;
        biascat[e] = bp[r];
    }
}

// biassym[b,i,l] = bm[b,i,l] + bm[b,l,i]
__global__ __launch_bounds__(256) void k_bias_sym(
    const float* __restrict__ bm, float* __restrict__ biassym)
{
    int rem = blockIdx.x*256 + threadIdx.x;     // < 36864
    int b = blockIdx.y;
    int i = rem / NG, l = rem % NG;
    biassym[(size_t)b*NN2 + rem] = bm[(size_t)b*NN2 + rem] + bm[(size_t)b*NN2 + l*NG + i];
}

// ------------------------------------------------------------------
// 128x128 MFMA tile, K=256, double-buffered gl_lds + counted vmcnt.
// 4 waves, each 64x64 = 4x4 frags of 16x16x32.
// ------------------------------------------------------------------
static __device__ __forceinline__ void gemm128_dbuf(
    const u16* __restrict__ A, const u16* __restrict__ B,
    u16* As, u16* Bs, f32x4 acc[4][4], int t)
{
    const int lane = t & 63, w = t >> 6;
    const int wm = (w>>1)*64, wn = (w&1)*64;
    int offA[4], offB[4];
    #pragma unroll
    for (int f=0; f<4; f++){
        int ra = wm + f*16 + (lane&15);
        offA[f] = ra*32 + (((lane>>4) ^ ((ra>>1)&3)) << 3);
        int rb = wn + f*16 + (lane&15);
        offB[f] = rb*32 + (((lane>>4) ^ ((rb>>1)&3)) << 3);
    }
    auto stage = [&](int buf, int k0){
        #pragma unroll
        for (int it=0; it<2; it++){
            int c = it*256 + t;
            int row = c >> 2;
            int ks  = (c&3) ^ ((row>>1)&3);
            gl_lds16(A + (size_t)row*DD + k0 + ks*8, As + buf*4096 + c*8);
            gl_lds16(B + (size_t)row*DD + k0 + ks*8, Bs + buf*4096 + c*8);
        }
    };
    stage(0, 0);
    for (int ks=0; ks<8; ks++){
        if (ks<7){
            stage((ks+1)&1, (ks+1)*32);
            asm volatile("s_waitcnt vmcnt(4)" ::: "memory");
        } else {
            asm volatile("s_waitcnt vmcnt(0)" ::: "memory");
        }
        __builtin_amdgcn_s_barrier();
        const u16* Ab = As + (ks&1)*4096;
        const u16* Bb = Bs + (ks&1)*4096;
        bf16x8 a[4], b[4];
        #pragma unroll
        for (int f=0; f<4; f++) a[f] = *(const bf16x8*)(Ab + offA[f]);
        #pragma unroll
        for (int f=0; f<4; f++) b[f] = *(const bf16x8*)(Bb + offB[f]);
        #pragma unroll
        for (int mf=0; mf<4; mf++)
            #pragma unroll
            for (int nf=0; nf<4; nf++)
                acc[mf][nf] = __builtin_amdgcn_mfma_f32_16x16x32_bf16(a[mf], b[nf], acc[mf][nf], 0, 0, 0);
        __builtin_amdgcn_s_barrier();
    }
}

// fused q/k/v/g projection: Eb[73728x256] @ Wcat^T[1024x256]
// grid 4608 1D; blk&7 ~ XCD; per XCD: 72 m-tiles x 8 n-tiles, n innermost
__global__ __launch_bounds__(256) void k_proj_mfma(
    const u16* __restrict__ Eb, const u16* __restrict__ Wcat,
    const float* __restrict__ biascat,
    u16* __restrict__ qb, u16* __restrict__ kb,
    u16* __restrict__ vb, u16* __restrict__ gb)
{
    __shared__ u16 As[2*4096];
    __shared__ u16 Bs[2*4096];
    const int blk = blockIdx.x;
    const int xj = blk & 7, xi = blk >> 3;          // xi in [0,576)
    const int m0 = (xj*72 + (xi>>3)) * 128;
    const int n0 = (xi & 7) * 128;
    const int t = threadIdx.x, lane = t&63, w = t>>6;
    f32x4 acc[4][4];
    #pragma unroll
    for (int i=0;i<4;i++)
        #pragma unroll
        for (int j=0;j<4;j++) acc[i][j] = f32x4{0.f,0.f,0.f,0.f};
    gemm128_dbuf(Eb + (size_t)m0*DD, Wcat + (size_t)n0*DD, As, Bs, acc, t);

    const int p = n0 >> 8;
    u16* outp = p==0?qb : p==1?kb : p==2?vb : gb;
    const int wm = (w>>1)*64, wn = (w&1)*64;
    #pragma unroll
    for (int mf=0; mf<4; mf++){
        int m = m0 + wm + mf*16 + (lane>>4)*4;
        #pragma unroll
        for (int nf=0; nf<4; nf++){
            int gn = n0 + wn + nf*16 + (lane&15);
            float bias = biascat[gn];
            int col = gn & 255;
            #pragma unroll
            for (int r=0; r<4; r++){
                float v = acc[mf][nf][r] + bias;
                if (p==3) v = 1.0f/(1.0f+__expf(-v));
                outp[(size_t)(m+r)*DD + col] = f2bfu(v);
            }
        }
    }
}

// final: out = relu(hb @ Wob^T + bo), f32; grid 1152 1D swizzled
__global__ __launch_bounds__(256) void k_final_mfma(
    const u16* __restrict__ hb, const u16* __restrict__ Wob,
    const float* __restrict__ bo, float* __restrict__ out)
{
    __shared__ u16 As[2*4096];
    __shared__ u16 Bs[2*4096];
    const int blk = blockIdx.x;
    const int xj = blk & 7, xi = blk >> 3;          // xi in [0,144)
    const int m0 = (xj*72 + (xi>>1)) * 128;
    const int n0 = (xi & 1) * 128;
    const int t = threadIdx.x, lane = t&63, w = t>>6;
    f32x4 acc[4][4];
    #pragma unroll
    for (int i=0;i<4;i++)
        #pragma unroll
        for (int j=0;j<4;j++) acc[i][j] = f32x4{0.f,0.f,0.f,0.f};
    gemm128_dbuf(hb + (size_t)m0*DD, Wob + (size_t)n0*DD, As, Bs, acc, t);

    const int wm = (w>>1)*64, wn = (w&1)*64;
    #pragma unroll
    for (int mf=0; mf<4; mf++){
        int m = m0 + wm + mf*16 + (lane>>4)*4;
        #pragma unroll
        for (int nf=0; nf<4; nf++){
            int n = n0 + wn + nf*16 + (lane&15);
            float bias = bo[n];
            #pragma unroll
            for (int r=0; r<4; r++)
                out[(size_t)(m+r)*DD + n] = fmaxf(acc[mf][nf][r] + bias, 0.0f);
        }
    }
}

// ------------------------------------------------------------------
// scores: 192x192x256 GEMM per block, bf16 out (scaled by 1/16).
// MODE 0 (t1): block (b,i): S1[b,i,j,l] = q[b,i,j,:].k[b,i,l,:]/16
// MODE 1 (t2): block (b,j): S2T[b,j,i,l] = q[b,i,j,:].k[b,l,j,:]/16
// Both write a contiguous 192x192 tile — no RMW.
// ------------------------------------------------------------------
template<int MODE>
__global__ __launch_bounds__(512, 2) void k_scores(
    const u16* __restrict__ q, const u16* __restrict__ kmat,
    u16* __restrict__ outS)
{
    __shared__ u16 As[2][NG*64];
    __shared__ u16 Bs[2][NG*64];
    const int z = blockIdx.x, b = z/NG, r = z%NG;
    const int t = threadIdx.x, lane = t&63, w = t>>6;
    const int wm = (w&3)*48, wn = (w>>2)*96;
    const size_t astr = MODE ? (size_t)NG*DD : (size_t)DD;
    const u16* Ab = MODE ? q    + ((size_t)b*NN2 + r)*DD : q    + ((size_t)b*NG + r)*NG*DD;
    const u16* Bb = MODE ? kmat + ((size_t)b*NN2 + r)*DD : kmat + ((size_t)b*NG + r)*NG*DD;

    f32x4 acc[3][6];
    #pragma unroll
    for (int i=0;i<3;i++)
        #pragma unroll
        for (int j=0;j<6;j++) acc[i][j] = f32x4{0.f,0.f,0.f,0.f};

    int offA[3], offB[6];
    #pragma unroll
    for (int mf=0; mf<3; mf++){
        int x = wm + mf*16 + (lane&15);
        offA[mf] = x*64 + (((lane>>4)<<3) ^ swz3(x));
    }
    #pragma unroll
    for (int nf=0; nf<6; nf++){
        int x = wn + nf*16 + (lane&15);
        offB[nf] = x*64 + (((lane>>4)<<3) ^ swz3(x));
    }

    auto stage = [&](int buf, int k0){
        #pragma unroll
        for (int rr=0; rr<3; rr++){
            int c = t + rr*512;
            int x = c>>3, l8e = (c&7)<<3;
            size_t ro = (size_t)x*astr + k0;
            gl_lds16(Ab + ro + (l8e ^ swz3(x)), &As[buf][c*8]);
            gl_lds16(Bb + ro + (l8e ^ swz3(x)), &Bs[buf][c*8]);
        }
    };

    stage(0, 0);
    for (int ks=0; ks<4; ks++){
        if (ks<3){
            stage((ks+1)&1, (ks+1)*64);
            asm volatile("s_waitcnt vmcnt(6)" ::: "memory");
        } else {
            asm volatile("s_waitcnt vmcnt(0)" ::: "memory");
        }
        __builtin_amdgcn_s_barrier();
        const u16* A = &As[ks&1][0];
        const u16* B = &Bs[ks&1][0];
        #pragma unroll
        for (int kk=0; kk<2; kk++){
            bf16x8 a[3];
            #pragma unroll
            for (int mf=0; mf<3; mf++) a[mf] = *(const bf16x8*)(A + (offA[mf]^(kk<<5)));
            #pragma unroll
            for (int nf=0; nf<6; nf++){
                bf16x8 bf = *(const bf16x8*)(B + (offB[nf]^(kk<<5)));
                #pragma unroll
                for (int mf=0; mf<3; mf++)
                    acc[mf][nf] = __builtin_amdgcn_mfma_f32_16x16x32_bf16(a[mf], bf, acc[mf][nf], 0, 0, 0);
            }
        }
        __builtin_amdgcn_s_barrier();
    }

    u16* outb = outS + ((size_t)b*NG + r)*NN2;
    #pragma unroll
    for (int mf=0; mf<3; mf++){
        #pragma unroll
        for (int nf=0; nf<6; nf++){
            int lcol = wn + nf*16 + (lane&15);
            #pragma unroll
            for (int r4=0; r4<4; r4++){
                int x = wm + mf*16 + (lane>>4)*4 + r4;   // j (M0) or i (M1)
                outb[(size_t)x*NG + lcol] = f2bfu(acc[mf][nf][r4]*0.0625f);
            }
        }
    }
}

// ------------------------------------------------------------------
// softmax over l: s = S1[b,i,j,l] + S2T[b,j,i,l] + biassym[b,i,l]
// writes bf16 alpha[b,i,j,:] and alphaT[b,j,i,:]
// ------------------------------------------------------------------
__global__ __launch_bounds__(256) void k_softmax(
    const u16* __restrict__ S1, const u16* __restrict__ S2T,
    const float* __restrict__ biassym,
    u16* __restrict__ alpha, u16* __restrict__ alphaT)
{
    int rr   = blockIdx.x*4 + (threadIdx.x >> 6);   // i*NG + j
    int lane = threadIdx.x & 63;
    int b = blockIdx.y;
    int i = rr / NG, j = rr % NG;
    const u16* r1 = S1  + ((size_t)b*NN2 + rr)*NG;
    const u16* r2 = S2T + ((size_t)b*NN2 + (size_t)j*NG + i)*NG;
    const float* bs = biassym + ((size_t)b*NG + i)*NG;
    float vals[3];
    float mx = -1e30f;
    #pragma unroll
    for (int tt=0; tt<3; tt++){
        int l = lane + tt*64;
        float s = bfu2f(r1[l]) + bfu2f(r2[l]) + bs[l];
        vals[tt] = s;
        mx = fmaxf(mx, s);
    }
    #pragma unroll
    for (int off=32; off; off>>=1) mx = fmaxf(mx, __shfl_xor(mx, off));
    float sum = 0.f;
    #pragma unroll
    for (int tt=0; tt<3; tt++){ vals[tt] = __expf(vals[tt]-mx); sum += vals[tt]; }
    #pragma unroll
    for (int off=32; off; off>>=1) sum += __shfl_xor(sum, off);
    float inv = 1.0f/sum;
    u16* arow1 = alpha  + ((size_t)b*NN2 + rr)*NG;
    u16* arow2 = alphaT + ((size_t)b*NN2 + (size_t)j*NG + i)*NG;
    #pragma unroll
    for (int tt=0; tt<3; tt++){
        u16 vq = f2bfu(vals[tt]*inv);
        arow1[lane + tt*64] = vq;
        arow2[lane + tt*64] = vq;
    }
}

// ------------------------------------------------------------------
// attnout: block (bi, dhalf): out[192 j x 128 d] = A1@V1^T + A2@V2^T, gated.
// ------------------------------------------------------------------
__global__ __launch_bounds__(512, 4) void k_attnout(
    const u16* __restrict__ alpha, const u16* __restrict__ alphaT,
    const u16* __restrict__ vb, const u16* __restrict__ gb, u16* __restrict__ hb)
{
    __shared__ u16 AsL[2][NG*64];    // 2 x 24.0 KiB
    __shared__ u16 Vs[128*64];       // 16 KiB
    const int z = blockIdx.x, bi = z>>1, dh = z&1;
    const int b = bi/NG, i = bi%NG;
    const int dbase = dh*128;
    const int t = threadIdx.x, lane = t&63, w = t>>6;
    const int wm = (w&1)*96, wn = (w>>1)*32;

    const u16* Abase0 = alpha  + (size_t)bi*NN2;
    const u16* Abase1 = alphaT + (size_t)bi*NN2;
    const u16* V0 = vb + (size_t)bi*NG*DD + dbase;             // + l*DD
    const u16* V1 = vb + ((size_t)b*NG*NG + i)*DD + dbase;     // + l*NG*DD

    f32x4 acc[6][2];
    #pragma unroll
    for (int m=0;m<6;m++)
        #pragma unroll
        for (int n=0;n<2;n++) acc[m][n] = f32x4{0.f,0.f,0.f,0.f};

    int offA[6], offB[2];
    #pragma unroll
    for (int mf=0; mf<6; mf++){
        int j = wm + mf*16 + (lane&15);
        offA[mf] = j*64 + (((lane>>4)<<3) ^ swz3(j));
    }
    #pragma unroll
    for (int nf=0; nf<2; nf++){
        int d = wn + nf*16 + (lane&15);
        offB[nf] = d*64 + (((lane>>4)<<3) ^ swz3(d));
    }

    int4 vr[2];
    auto stageA = [&](int u, int buf){
        const u16* Ab = (u>=3) ? Abase1 : Abase0;
        int ls = (u>=3 ? u-3 : u)*64;
        #pragma unroll
        for (int rr=0; rr<3; rr++){
            int c = t + rr*512;
            int j = c>>3, l8e = (c&7)<<3;
            gl_lds16(Ab + (size_t)j*NG + ls + (l8e ^ swz3(j)), &AsL[buf][c*8]);
        }
    };
    auto loadV = [&](int u){
        int p = (u>=3), ls = (u>=3 ? u-3 : u)*64;
        #pragma unroll
        for (int rr=0; rr<2; rr++){
            int c = t + rr*512;
            int l = ls + (c>>4), d0 = (c&15)*8;
            const u16* src = p ? (V1 + (size_t)l*NG*DD + d0) : (V0 + (size_t)l*DD + d0);
            vr[rr] = *(const int4*)src;
        }
    };

    stageA(0, 0);
    loadV(0);
    for (int u=0; u<6; u++){
        #pragma unroll
        for (int rr=0; rr<2; rr++){
            int c = t + rr*512;
            int l = c>>4;
            l &= 63;
            int d0 = (c&15)*8, c3 = c&7;
            ushort* vp = (ushort*)&vr[rr];
            #pragma unroll
            for (int qd=0; qd<8; qd++)
                Vs[(d0+qd)*64 + (l ^ ((qd^c3)<<3))] = vp[qd];
        }
        if (u<5){ stageA(u+1, (u+1)&1); loadV(u+1); }
        asm volatile("s_waitcnt lgkmcnt(0)" ::: "memory");
        __builtin_amdgcn_s_barrier();
        const u16* A = &AsL[u&1][0];
        #pragma unroll
        for (int kk=0; kk<2; kk++){
            bf16x8 bfr[2];
            #pragma unroll
            for (int nf=0; nf<2; nf++) bfr[nf] = *(const bf16x8*)(Vs + (offB[nf]^(kk<<5)));
            #pragma unroll
            for (int mf=0; mf<6; mf++){
                bf16x8 afr = *(const bf16x8*)(A + (offA[mf]^(kk<<5)));
                acc[mf][0] = __builtin_amdgcn_mfma_f32_16x16x32_bf16(afr, bfr[0], acc[mf][0], 0, 0, 0);
                acc[mf][1] = __builtin_amdgcn_mfma_f32_16x16x32_bf16(afr, bfr[1], acc[mf][1], 0, 0, 0);
            }
        }
        __builtin_amdgcn_s_barrier();
    }

    #pragma unroll
    for (int mf=0; mf<6; mf++){
        #pragma unroll
        for (int nf=0; nf<2; nf++){
            #pragma unroll
            for (int r4=0; r4<4; r4++){
                int j = wm + mf*16 + (lane>>4)*4 + r4;
                int d = dbase + wn + nf*16 + (lane&15);
                size_t idx = ((size_t)bi*NG + j)*DD + d;
                hb[idx] = f2bfu(bfu2f(gb[idx]) * acc[mf][nf][r4]);
            }
        }
    }
}

// ------------------------------------------------------------------
// Workspace (total ~208.9 MB, proven level):
//  A [0, 56.6M): Eb (dead after proj) -> S1+S2T bf16 (dead after softmax) -> hb
//  B [56.6, 94.4M): qb -> alpha   (after t1/t2)
//  C [94.4, 132.1M): kb -> alphaT (after t1/t2)
//  D: vb   E: gb   tail: bm, biassym, Wcat, Wob, biascat
// ------------------------------------------------------------------
extern "C" void kernel_launch(void* const* d_in, const int* in_sizes, int n_in,
                              void* d_out, int out_size, void* d_ws, size_t ws_size,
                              hipStream_t stream)
{
    const float* E  = (const float*)d_in[0];
    const float* Wq = (const float*)d_in[1];  const float* bq = (const float*)d_in[2];
    const float* Wk = (const float*)d_in[3];  const float* bk = (const float*)d_in[4];
    const float* Wv = (const float*)d_in[5];  const float* bv = (const float*)d_in[6];
    const float* Wb = (const float*)d_in[7];  const float* bb = (const float*)d_in[8];
    const float* Wg = (const float*)d_in[9];  const float* bg = (const float*)d_in[10];
    const float* Wo = (const float*)d_in[11]; const float* bo = (const float*)d_in[12];
    float* out = (float*)d_out;

    const size_t BF = (size_t)MT*DD*2;              // 37,748,736
    const size_t SC = (size_t)NB*NG*NG*NG*4;        // 56,623,104
    char* ws = (char*)d_ws;
    u16* Eb  = (u16*)ws;
    u16* S1  = (u16*)ws;                            // 28.3 MB
    u16* S2T = (u16*)(ws + SC/2);                   // 28.3 MB
    u16* hb  = (u16*)ws;
    u16* qb = (u16*)(ws + SC);           u16* alpha  = qb;
    u16* kb = (u16*)(ws + SC + BF);      u16* alphaT = kb;
    u16* vb = (u16*)(ws + SC + 2*BF);
    u16* gb = (u16*)(ws + SC + 3*BF);
    size_t tail = SC + 4*BF;
    float* bm      = (float*)(ws + tail); tail += (size_t)MT*4;
    float* biassym = (float*)(ws + tail); tail += (size_t)MT*4;
    u16* Wcat      = (u16*)(ws + tail);   tail += (size_t)1024*DD*2;
    u16* Wob       = (u16*)(ws + tail);   tail += (size_t)DD*DD*2;
    float* biascat = (float*)(ws + tail); tail += 1024*4;
    (void)ws_size;

    k_cast_w   <<<dim3(256), 256, 0, stream>>>(Wq,Wk,Wv,Wg,Wo, bq,bk,bv,bg, Wcat, Wob, biascat);
    k_cast_eb  <<<dim3(9216), 256, 0, stream>>>(E, Wb, bb, Eb, bm);
    k_proj_mfma<<<dim3(4608), 256, 0, stream>>>(Eb, Wcat, biascat, qb, kb, vb, gb);
    k_bias_sym <<<dim3(NN2/256, NB), 256, 0, stream>>>(bm, biassym);
    k_scores<0><<<dim3(NB*NG), 512, 0, stream>>>(qb, kb, S1);
    k_scores<1><<<dim3(NB*NG), 512, 0, stream>>>(qb, kb, S2T);
    k_softmax  <<<dim3(NN2/4, NB), 256, 0, stream>>>(S1, S2T, biassym, alpha, alphaT);
    k_attnout  <<<dim3(NB*NG*2), 512, 0, stream>>>(alpha, alphaT, vb, gb, hb);
    k_final_mfma<<<dim3(1152), 256, 0, stream>>>(hb, Wob, bo, out);
}